// Round 2
// baseline (922.964 us; speedup 1.0000x reference)
//
#include <hip/hip_runtime.h>

#define NN 50000
#define NE 800000
#define HD 128

typedef short short8 __attribute__((ext_vector_type(8)));
typedef float floatx4 __attribute__((ext_vector_type(4)));
typedef unsigned short ushort4v __attribute__((ext_vector_type(4)));

static __device__ __forceinline__ unsigned short f2bf(float f) {
    unsigned int u = __float_as_uint(f);
    unsigned int lsb = (u >> 16) & 1u;
    u += 0x7fffu + lsb;
    return (unsigned short)(u >> 16);
}

static __device__ __forceinline__ floatx4 mfma16x16x32(short8 a, short8 b, floatx4 c) {
    asm("v_mfma_f32_16x16x32_bf16 %0, %1, %2, %0" : "+v"(c) : "v"(a), "v"(b));
    return c;
}

// Hazard guards: inline-asm MFMA is invisible to LLVM's GCNHazardRecognizer, so
// we insert the required wait-states manually. "+v" ties order: producers ->
// nops -> consumers.
#define NOPGUARD_INIT8(A) asm volatile("s_nop 3" \
  : "+v"(A[0]),"+v"(A[1]),"+v"(A[2]),"+v"(A[3]),"+v"(A[4]),"+v"(A[5]),"+v"(A[6]),"+v"(A[7]))
#define NOPGUARD8(A) asm volatile("s_nop 7\ns_nop 7" \
  : "+v"(A[0]),"+v"(A[1]),"+v"(A[2]),"+v"(A[3]),"+v"(A[4]),"+v"(A[5]),"+v"(A[6]),"+v"(A[7]))

// Pack weight matrices (row-major KxC fp32, C=128) into MFMA B-fragment layout:
// element index ((kk*8+n)*64+lane)*8+j  <->  k = kk*32 + (lane>>4)*8 + j, c = n*16 + (lane&15)
__global__ void pack_weights(const float* __restrict__ mW1, const float* __restrict__ mW2,
                             const float* __restrict__ uW1, const float* __restrict__ uW2,
                             unsigned short* __restrict__ W1p, unsigned short* __restrict__ W2p,
                             unsigned short* __restrict__ U1p, unsigned short* __restrict__ U2p) {
    int t = blockIdx.x * 256 + threadIdx.x;
    const float* src; unsigned short* dst; int kmax; int i;
    if (t < 40960)        { src = mW1; dst = W1p; kmax = 291; i = t; }
    else if (t < 57344)   { src = mW2; dst = W2p; kmax = 128; i = t - 40960; }
    else if (t < 90112)   { src = uW1; dst = U1p; kmax = 256; i = t - 57344; }
    else if (t < 106496)  { src = uW2; dst = U2p; kmax = 128; i = t - 90112; }
    else return;
    int j = i & 7;
    int lane = (i >> 3) & 63;
    int n = (i >> 9) & 7;
    int kk = i >> 12;
    int k = kk * 32 + ((lane >> 4) << 3) + j;
    int c = n * 16 + (lane & 15);
    float v = (k < kmax) ? src[k * 128 + c] : 0.0f;
    dst[i] = f2bf(v);
}

// Message MLP + atomic aggregation. 64 edges per block, 4 waves.
__global__ __launch_bounds__(256, 2)
void msg_kernel(const float* __restrict__ x, const int* __restrict__ ei,
                const float* __restrict__ ea, const float* __restrict__ cd,
                const unsigned short* __restrict__ W1p, const float* __restrict__ mb1,
                const unsigned short* __restrict__ W2p, const float* __restrict__ mb2,
                float* __restrict__ aggr) {
    __shared__ unsigned short sA[64 * 328];   // 64 edges x 320 feats (padded stride 328)
    __shared__ unsigned short sH[64 * 136];   // hidden tile, stride 136
    __shared__ int sSrc[64];
    __shared__ int sDst[64];

    const int tid = threadIdx.x;
    const int e0 = blockIdx.x * 64;

    if (tid < 64) {
        sSrc[tid] = ei[e0 + tid];
        sDst[tid] = ei[NE + e0 + tid];
    }
    __syncthreads();

    // Stage msg_input tile: layout [x_src(128) | x_dst(128) | edge_attr(32) | rel(3)+pad(29)]
    #pragma unroll
    for (int it = 0; it < 20; ++it) {
        int idx = it * 256 + tid;        // 0..5119 ; 80 float4-chunks per edge
        int e = idx / 80;
        int c = idx - e * 80;
        int f = c * 4;
        float4 v;
        if (f < 128) {
            v = *reinterpret_cast<const float4*>(x + sSrc[e] * 128 + f);
        } else if (f < 256) {
            v = *reinterpret_cast<const float4*>(x + sDst[e] * 128 + (f - 128));
        } else if (f < 288) {
            v = *reinterpret_cast<const float4*>(ea + (e0 + e) * 32 + (f - 256));
        } else if (f == 288) {
            int s = sSrc[e], d = sDst[e];
            v.x = cd[d * 3 + 0] - cd[s * 3 + 0];
            v.y = cd[d * 3 + 1] - cd[s * 3 + 1];
            v.z = cd[d * 3 + 2] - cd[s * 3 + 2];
            v.w = 0.0f;
        } else {
            v.x = v.y = v.z = v.w = 0.0f;
        }
        ushort4v w = { f2bf(v.x), f2bf(v.y), f2bf(v.z), f2bf(v.w) };
        *reinterpret_cast<ushort4v*>(&sA[e * 328 + f]) = w;
    }
    __syncthreads();

    const int lane = tid & 63;
    const int wid = tid >> 6;
    const int g = lane >> 4;
    const int lr = lane & 15;
    const int arow = wid * 16 + lr;

    // Layer 1: (64x320) @ (320x128)
    floatx4 acc[8];
    #pragma unroll
    for (int n = 0; n < 8; ++n)
        #pragma unroll
        for (int r = 0; r < 4; ++r) acc[n][r] = 0.0f;
    NOPGUARD_INIT8(acc);

    #pragma unroll
    for (int kk = 0; kk < 10; ++kk) {
        short8 a = *reinterpret_cast<const short8*>(&sA[arow * 328 + kk * 32 + g * 8]);
        const short8* wb = reinterpret_cast<const short8*>(W1p) + (kk * 8) * 64 + lane;
        #pragma unroll
        for (int n = 0; n < 8; ++n) {
            short8 b = wb[n * 64];
            acc[n] = mfma16x16x32(a, b, acc[n]);
        }
    }
    NOPGUARD8(acc);

    // bias + ReLU -> sH (bf16)
    #pragma unroll
    for (int n = 0; n < 8; ++n) {
        float bias = mb1[n * 16 + lr];
        #pragma unroll
        for (int r = 0; r < 4; ++r) {
            int row = wid * 16 + g * 4 + r;
            float v = acc[n][r] + bias;
            v = fmaxf(v, 0.0f);
            sH[row * 136 + n * 16 + lr] = f2bf(v);
        }
    }
    __syncthreads();

    // Layer 2: (64x128) @ (128x128)
    floatx4 acc2[8];
    #pragma unroll
    for (int n = 0; n < 8; ++n)
        #pragma unroll
        for (int r = 0; r < 4; ++r) acc2[n][r] = 0.0f;
    NOPGUARD_INIT8(acc2);

    #pragma unroll
    for (int kk = 0; kk < 4; ++kk) {
        short8 a = *reinterpret_cast<const short8*>(&sH[arow * 136 + kk * 32 + g * 8]);
        const short8* wb = reinterpret_cast<const short8*>(W2p) + (kk * 8) * 64 + lane;
        #pragma unroll
        for (int n = 0; n < 8; ++n) {
            short8 b = wb[n * 64];
            acc2[n] = mfma16x16x32(a, b, acc2[n]);
        }
    }
    NOPGUARD8(acc2);

    // bias + atomic scatter into aggr[dst]
    #pragma unroll
    for (int n = 0; n < 8; ++n) {
        float bias = mb2[n * 16 + lr];
        #pragma unroll
        for (int r = 0; r < 4; ++r) {
            int row = wid * 16 + g * 4 + r;
            int dn = sDst[row];
            atomicAdd(&aggr[dn * 128 + n * 16 + lr], acc2[n][r] + bias);
        }
    }
}

// Node update MLP + residual + LayerNorm. 64 nodes per block, 4 waves.
// aggr aliases d_out: each block stages its own 64 aggr rows into LDS before
// any thread of this block overwrites those same rows; blocks touch disjoint rows.
__global__ __launch_bounds__(256, 2)
void node_kernel(const float* __restrict__ x, const float* __restrict__ aggr,
                 const unsigned short* __restrict__ U1p, const float* __restrict__ ub1,
                 const unsigned short* __restrict__ U2p, const float* __restrict__ ub2,
                 const float* __restrict__ gamma, const float* __restrict__ beta,
                 float* __restrict__ out) {
    __shared__ unsigned short sA[64 * 264];   // 64 nodes x 256 feats (stride 264)
    __shared__ unsigned short sH[64 * 136];

    const int tid = threadIdx.x;
    const int n0 = blockIdx.x * 64;

    // Stage [x | aggr] tile
    #pragma unroll
    for (int it = 0; it < 16; ++it) {
        int idx = it * 256 + tid;       // 0..4095 ; 64 chunks per node
        int e = idx >> 6;
        int f = (idx & 63) * 4;
        int nd = n0 + e;
        if (nd >= NN) nd = NN - 1;
        float4 v;
        if (f < 128) v = *reinterpret_cast<const float4*>(x + nd * 128 + f);
        else         v = *reinterpret_cast<const float4*>(aggr + nd * 128 + (f - 128));
        ushort4v w = { f2bf(v.x), f2bf(v.y), f2bf(v.z), f2bf(v.w) };
        *reinterpret_cast<ushort4v*>(&sA[e * 264 + f]) = w;
    }
    __syncthreads();

    const int lane = tid & 63;
    const int wid = tid >> 6;
    const int g = lane >> 4;
    const int lr = lane & 15;
    const int arow = wid * 16 + lr;

    floatx4 acc[8];
    #pragma unroll
    for (int n = 0; n < 8; ++n)
        #pragma unroll
        for (int r = 0; r < 4; ++r) acc[n][r] = 0.0f;
    NOPGUARD_INIT8(acc);

    #pragma unroll
    for (int kk = 0; kk < 8; ++kk) {
        short8 a = *reinterpret_cast<const short8*>(&sA[arow * 264 + kk * 32 + g * 8]);
        const short8* wb = reinterpret_cast<const short8*>(U1p) + (kk * 8) * 64 + lane;
        #pragma unroll
        for (int n = 0; n < 8; ++n) {
            short8 b = wb[n * 64];
            acc[n] = mfma16x16x32(a, b, acc[n]);
        }
    }
    NOPGUARD8(acc);

    #pragma unroll
    for (int n = 0; n < 8; ++n) {
        float bias = ub1[n * 16 + lr];
        #pragma unroll
        for (int r = 0; r < 4; ++r) {
            int row = wid * 16 + g * 4 + r;
            float v = acc[n][r] + bias;
            v = fmaxf(v, 0.0f);
            sH[row * 136 + n * 16 + lr] = f2bf(v);
        }
    }
    __syncthreads();

    floatx4 acc2[8];
    #pragma unroll
    for (int n = 0; n < 8; ++n)
        #pragma unroll
        for (int r = 0; r < 4; ++r) acc2[n][r] = 0.0f;
    NOPGUARD_INIT8(acc2);

    #pragma unroll
    for (int kk = 0; kk < 4; ++kk) {
        short8 a = *reinterpret_cast<const short8*>(&sH[arow * 136 + kk * 32 + g * 8]);
        const short8* wb = reinterpret_cast<const short8*>(U2p) + (kk * 8) * 64 + lane;
        #pragma unroll
        for (int n = 0; n < 8; ++n) {
            short8 b = wb[n * 64];
            acc2[n] = mfma16x16x32(a, b, acc2[n]);
        }
    }
    NOPGUARD8(acc2);

    // Epilogue: residual + LayerNorm, fully in registers.
    // C layout: row = wid*16 + g*4 + r, col = n*16 + lr. For fixed (g,r) the 16 lanes
    // with lr=0..15 hold all 128 cols of one row -> shfl_xor(1,2,4,8) row-reduce.
    #pragma unroll
    for (int r = 0; r < 4; ++r) {
        int row = wid * 16 + g * 4 + r;
        int nd = n0 + row;
        int ndc = (nd < NN) ? nd : (NN - 1);
        float vals[8];
        float s1 = 0.0f, s2 = 0.0f;
        #pragma unroll
        for (int n = 0; n < 8; ++n) {
            int col = n * 16 + lr;
            float v = acc2[n][r] + ub2[col] + x[ndc * 128 + col];
            vals[n] = v;
            s1 += v;
            s2 += v * v;
        }
        #pragma unroll
        for (int m = 1; m < 16; m <<= 1) {
            s1 += __shfl_xor(s1, m);
            s2 += __shfl_xor(s2, m);
        }
        float mean = s1 * (1.0f / 128.0f);
        float var = s2 * (1.0f / 128.0f) - mean * mean;
        float inv = rsqrtf(var + 1e-5f);
        if (nd < NN) {
            #pragma unroll
            for (int n = 0; n < 8; ++n) {
                int col = n * 16 + lr;
                out[nd * 128 + col] = (vals[n] - mean) * inv * gamma[col] + beta[col];
            }
        }
    }
}

extern "C" void kernel_launch(void* const* d_in, const int* in_sizes, int n_in,
                              void* d_out, int out_size, void* d_ws, size_t ws_size,
                              hipStream_t stream) {
    const float* x     = (const float*)d_in[0];
    const int*   ei    = (const int*)d_in[1];
    const float* ea    = (const float*)d_in[2];
    const float* cd    = (const float*)d_in[3];
    const float* mW1   = (const float*)d_in[4];
    const float* mb1   = (const float*)d_in[5];
    const float* mW2   = (const float*)d_in[6];
    const float* mb2   = (const float*)d_in[7];
    const float* uW1   = (const float*)d_in[8];
    const float* ub1   = (const float*)d_in[9];
    const float* uW2   = (const float*)d_in[10];
    const float* ub2   = (const float*)d_in[11];
    const float* gamma = (const float*)d_in[12];
    const float* beta  = (const float*)d_in[13];
    float* out = (float*)d_out;

    char* ws = (char*)d_ws;
    unsigned short* W1p = (unsigned short*)(ws);            // 81920 B
    unsigned short* W2p = (unsigned short*)(ws + 81920);    // 32768 B
    unsigned short* U1p = (unsigned short*)(ws + 114688);   // 65536 B
    unsigned short* U2p = (unsigned short*)(ws + 180224);   // 32768 B

    // aggr lives in d_out (exactly NN*HD floats): avoids betting on ws_size.
    float* aggr = out;

    hipMemsetAsync(aggr, 0, (size_t)NN * HD * sizeof(float), stream);
    pack_weights<<<416, 256, 0, stream>>>(mW1, mW2, uW1, uW2, W1p, W2p, U1p, U2p);
    msg_kernel<<<NE / 64, 256, 0, stream>>>(x, ei, ea, cd, W1p, mb1, W2p, mb2, aggr);
    node_kernel<<<(NN + 63) / 64, 256, 0, stream>>>(x, aggr, U1p, ub1, U2p, ub2, gamma, beta, out);
}